// Round 1
// baseline (2518.713 us; speedup 1.0000x reference)
//
#include <hip/hip_runtime.h>
#include <math.h>

// ---------------------------------------------------------------------------
// Qwen2MoE decoder layer, MI355X (gfx950).
// fp16-staged MFMA GEMMs (f32 accum), fp32 flash attention, fp32 router/top-k.
// Workspace budget ~334 MB.
// ---------------------------------------------------------------------------

typedef _Float16 h16;
typedef _Float16 half8 __attribute__((ext_vector_type(8)));
typedef float f32x4 __attribute__((ext_vector_type(4)));

#define S_ 2048
#define H_ 2048
#define NH_ 16
#define D_ 128
#define E_ 8
#define TOPK_ 4
#define IE_ 1408
#define IS_ 5632
#define NQKV_ 6144

// ---------------------------------------------------------------------------
// Transpose fp32 (R x C) -> fp16 (C x R), batched over z.
// ---------------------------------------------------------------------------
__global__ __launch_bounds__(256) void transpose_kernel(
    const float* __restrict__ in, h16* __restrict__ out,
    int R, int C, long long inZ, long long outZ) {
  in  += (size_t)blockIdx.z * inZ;
  out += (size_t)blockIdx.z * outZ;
  __shared__ float tile[32][33];
  int c0 = blockIdx.x * 32, r0 = blockIdx.y * 32;
  int tx = threadIdx.x & 31, ty = threadIdx.x >> 5;  // 32 x 8
#pragma unroll
  for (int i = 0; i < 4; i++)
    tile[ty + 8 * i][tx] = in[(size_t)(r0 + ty + 8 * i) * C + c0 + tx];
  __syncthreads();
#pragma unroll
  for (int i = 0; i < 4; i++)
    out[(size_t)(c0 + ty + 8 * i) * R + r0 + tx] = (h16)tile[tx][ty + 8 * i];
}

// ---------------------------------------------------------------------------
// RMSNorm: one block per row. Writes fp16 (and optionally fp32).
// ---------------------------------------------------------------------------
template <bool F32OUT>
__global__ __launch_bounds__(256) void rmsnorm_kernel(
    const float* __restrict__ x, const float* __restrict__ w,
    h16* __restrict__ outh, float* __restrict__ outf) {
  int row = blockIdx.x;
  const float* xr = x + (size_t)row * H_;
  float ss = 0.f;
  for (int i = threadIdx.x; i < H_; i += 256) { float v = xr[i]; ss += v * v; }
  for (int o = 32; o > 0; o >>= 1) ss += __shfl_down(ss, o);
  __shared__ float sred[4];
  if ((threadIdx.x & 63) == 0) sred[threadIdx.x >> 6] = ss;
  __syncthreads();
  float tot = sred[0] + sred[1] + sred[2] + sred[3];
  float r = rsqrtf(tot * (1.0f / H_) + 1e-6f);
  for (int i = threadIdx.x; i < H_; i += 256) {
    float hv = xr[i] * r * w[i];
    outh[(size_t)row * H_ + i] = (h16)hv;
    if (F32OUT) outf[(size_t)row * H_ + i] = hv;
  }
}

// ---------------------------------------------------------------------------
// Generic MFMA GEMM: C[M,N] = A[M,K] * Bt[N,K]^T. A,Bt fp16, accum fp32.
// BM=BN=128, BK=32, 256 threads (4 waves, each 64x64 = 4x4 MFMA 16x16x32).
// STORE: 0 = fp32 store, 1 = fp16 store, 2 = atomicAdd(rowscale[row]*val).
// ---------------------------------------------------------------------------
template <int STORE, bool RESID>
__global__ __launch_bounds__(256, 2) void gemm_kernel(
    const h16* __restrict__ A, const h16* __restrict__ Bt, void* __restrict__ Cv,
    int M, int N, int K,
    const float* __restrict__ resid, const float* __restrict__ rowscale) {
  __shared__ __align__(16) h16 As[128][40];
  __shared__ __align__(16) h16 Bs[128][40];
  const int tid = threadIdx.x;
  const int wave = tid >> 6, lane = tid & 63;
  const int wm = wave >> 1, wn = wave & 1;
  const int quad = lane >> 4, l16 = lane & 15;
  const int row0 = blockIdx.x * 128, col0 = blockIdx.y * 128;

  f32x4 acc[4][4];
#pragma unroll
  for (int i = 0; i < 4; i++)
#pragma unroll
    for (int j = 0; j < 4; j++) acc[i][j] = (f32x4){0.f, 0.f, 0.f, 0.f};

  const h16* Ablk = A + (size_t)row0 * K;
  const h16* Bblk = Bt + (size_t)col0 * K;
  const int ldr0 = tid >> 2;         // staging row (chunk 0)
  const int ldk = (tid & 3) * 8;     // 8 fp16 = 16B per chunk

  for (int k0 = 0; k0 < K; k0 += 32) {
#pragma unroll
    for (int i = 0; i < 2; i++) {
      int row = ldr0 + i * 64;
      uint4 av = *(const uint4*)(Ablk + (size_t)row * K + k0 + ldk);
      *(uint4*)(&As[row][ldk]) = av;
      uint4 bv = *(const uint4*)(Bblk + (size_t)row * K + k0 + ldk);
      *(uint4*)(&Bs[row][ldk]) = bv;
    }
    __syncthreads();
    half8 af[4], bfv[4];
#pragma unroll
    for (int mi = 0; mi < 4; mi++)
      af[mi] = *(const half8*)(&As[wm * 64 + mi * 16 + l16][quad * 8]);
#pragma unroll
    for (int ni = 0; ni < 4; ni++)
      bfv[ni] = *(const half8*)(&Bs[wn * 64 + ni * 16 + l16][quad * 8]);
#pragma unroll
    for (int mi = 0; mi < 4; mi++)
#pragma unroll
      for (int ni = 0; ni < 4; ni++)
        acc[mi][ni] = __builtin_amdgcn_mfma_f32_16x16x32_f16(af[mi], bfv[ni], acc[mi][ni], 0, 0, 0);
    __syncthreads();
  }

#pragma unroll
  for (int mi = 0; mi < 4; mi++) {
#pragma unroll
    for (int ni = 0; ni < 4; ni++) {
      int col = col0 + wn * 64 + ni * 16 + l16;
#pragma unroll
      for (int r = 0; r < 4; r++) {
        int row = row0 + wm * 64 + mi * 16 + quad * 4 + r;
        float val = acc[mi][ni][r];
        if (RESID) val += resid[(size_t)row * N + col];
        if (STORE == 0) ((float*)Cv)[(size_t)row * N + col] = val;
        else if (STORE == 1) ((h16*)Cv)[(size_t)row * N + col] = (h16)val;
        else atomicAdd(&((float*)Cv)[(size_t)row * N + col], rowscale[row] * val);
      }
    }
  }
}

// ---------------------------------------------------------------------------
// MoE GEMM. z = expert. PHASE 0: gathered A rows (rowidx) -> fp16 gu slots.
// PHASE 1: linear slot A rows -> atomicAdd roww[slot]*val into moe_acc[token].
// ---------------------------------------------------------------------------
template <int PHASE>
__global__ __launch_bounds__(256, 2) void moe_gemm_kernel(
    const h16* __restrict__ A, const h16* __restrict__ BtAll, void* __restrict__ Cv,
    const int* __restrict__ offs, const int* __restrict__ cnt,
    const int* __restrict__ rowidx, const float* __restrict__ roww,
    int N, int K) {
  const int e = blockIdx.z;
  const int Me = cnt[e], offe = offs[e];
  const int row0 = blockIdx.x * 128;
  if (row0 >= Me) return;
  const int col0 = blockIdx.y * 128;
  const h16* Bt = BtAll + (size_t)e * N * K;

  __shared__ __align__(16) h16 As[128][40];
  __shared__ __align__(16) h16 Bs[128][40];
  const int tid = threadIdx.x;
  const int wave = tid >> 6, lane = tid & 63;
  const int wm = wave >> 1, wn = wave & 1;
  const int quad = lane >> 4, l16 = lane & 15;

  f32x4 acc[4][4];
#pragma unroll
  for (int i = 0; i < 4; i++)
#pragma unroll
    for (int j = 0; j < 4; j++) acc[i][j] = (f32x4){0.f, 0.f, 0.f, 0.f};

  const int ldr0 = tid >> 2;
  const int ldk = (tid & 3) * 8;
  size_t abase[2]; bool aval[2];
#pragma unroll
  for (int i = 0; i < 2; i++) {
    int row = ldr0 + i * 64;
    aval[i] = (row0 + row) < Me;
    int slot = offe + row0 + row;
    int ar = aval[i] ? (PHASE == 0 ? rowidx[slot] : slot) : 0;
    abase[i] = (size_t)ar * K;
  }

  for (int k0 = 0; k0 < K; k0 += 32) {
#pragma unroll
    for (int i = 0; i < 2; i++) {
      int row = ldr0 + i * 64;
      uint4 av = {0, 0, 0, 0};
      if (aval[i]) av = *(const uint4*)(A + abase[i] + k0 + ldk);
      *(uint4*)(&As[row][ldk]) = av;
      uint4 bv = *(const uint4*)(Bt + (size_t)(col0 + row) * K + k0 + ldk);
      *(uint4*)(&Bs[row][ldk]) = bv;
    }
    __syncthreads();
    half8 af[4], bfv[4];
#pragma unroll
    for (int mi = 0; mi < 4; mi++)
      af[mi] = *(const half8*)(&As[wm * 64 + mi * 16 + l16][quad * 8]);
#pragma unroll
    for (int ni = 0; ni < 4; ni++)
      bfv[ni] = *(const half8*)(&Bs[wn * 64 + ni * 16 + l16][quad * 8]);
#pragma unroll
    for (int mi = 0; mi < 4; mi++)
#pragma unroll
      for (int ni = 0; ni < 4; ni++)
        acc[mi][ni] = __builtin_amdgcn_mfma_f32_16x16x32_f16(af[mi], bfv[ni], acc[mi][ni], 0, 0, 0);
    __syncthreads();
  }

#pragma unroll
  for (int mi = 0; mi < 4; mi++) {
#pragma unroll
    for (int ni = 0; ni < 4; ni++) {
      int col = col0 + wn * 64 + ni * 16 + l16;
#pragma unroll
      for (int r = 0; r < 4; r++) {
        int lrow = wm * 64 + mi * 16 + quad * 4 + r;
        if (row0 + lrow < Me) {
          int slot = offe + row0 + lrow;
          float val = acc[mi][ni][r];
          if (PHASE == 0) {
            ((h16*)Cv)[(size_t)slot * N + col] = (h16)val;
          } else {
            int token = rowidx[slot];
            atomicAdd(&((float*)Cv)[(size_t)token * N + col], roww[slot] * val);
          }
        }
      }
    }
  }
}

// ---------------------------------------------------------------------------
// RoPE + bias, in-place on qkv fp32 (S x 6144). One thread per (s,h,d<64).
// ---------------------------------------------------------------------------
__global__ __launch_bounds__(256) void rope_kernel(
    float* __restrict__ qkv, const float* __restrict__ bq,
    const float* __restrict__ bk, const float* __restrict__ bv) {
  int idx = blockIdx.x * 256 + threadIdx.x;
  int d = idx & 63;
  int h = (idx >> 6) & (NH_ - 1);
  int s = idx >> 10;
  float inv = powf(1.0e6f, -(float)d * (1.0f / 64.0f));
  float ang = (float)s * inv;
  float sn, c;
  sincosf(ang, &sn, &c);
  float* base = qkv + (size_t)s * NQKV_;
  int iq = h * 128 + d;
  float q1 = base[iq] + bq[iq];
  float q2 = base[iq + 64] + bq[iq + 64];
  base[iq] = q1 * c - q2 * sn;
  base[iq + 64] = q2 * c + q1 * sn;
  float k1 = base[2048 + iq] + bk[iq];
  float k2 = base[2048 + iq + 64] + bk[iq + 64];
  base[2048 + iq] = k1 * c - k2 * sn;
  base[2048 + iq + 64] = k2 * c + k1 * sn;
  base[4096 + iq] += bv[iq];
  base[4096 + iq + 64] += bv[iq + 64];
}

// ---------------------------------------------------------------------------
// Flash attention, fp32, causal. Block = (qb 32 rows, head). 256 threads.
// ---------------------------------------------------------------------------
__global__ __launch_bounds__(256, 2) void attn_kernel(
    const float* __restrict__ qkv, h16* __restrict__ attnh) {
  const int qb = blockIdx.x;
  const int hd = blockIdx.y;
  __shared__ __align__(16) float qs[32][132];
  __shared__ __align__(16) float ks[32][132];
  __shared__ __align__(16) float vs[32][132];
  __shared__ float ps[32][33];
  __shared__ float red[32][8];
  __shared__ float mrow[32], lrow[32], arow[32];
  const int tid = threadIdx.x;
  const int r = tid >> 3, jg = tid & 7, c0 = jg * 16;

  for (int i = tid; i < 32 * 32; i += 256) {
    int row = i >> 5, d4 = (i & 31) << 2;
    *(float4*)&qs[row][d4] =
        *(const float4*)&qkv[(size_t)(qb * 32 + row) * NQKV_ + hd * 128 + d4];
  }
  if (tid < 32) { mrow[tid] = -3.0e38f; lrow[tid] = 0.f; }
  float o[16];
#pragma unroll
  for (int i = 0; i < 16; i++) o[i] = 0.f;
  __syncthreads();

  const float scale = 0.08838834764831845f;  // 1/sqrt(128)
  for (int kc = 0; kc <= qb; kc++) {
    for (int i = tid; i < 32 * 32; i += 256) {
      int row = i >> 5, d4 = (i & 31) << 2;
      size_t g = (size_t)(kc * 32 + row) * NQKV_ + hd * 128 + d4;
      *(float4*)&ks[row][d4] = *(const float4*)&qkv[g + 2048];
      *(float4*)&vs[row][d4] = *(const float4*)&qkv[g + 4096];
    }
    __syncthreads();

    float sc0 = 0.f, sc1 = 0.f, sc2 = 0.f, sc3 = 0.f;
    {
      const float4* qr = (const float4*)&qs[r][0];
      const float4* k0r = (const float4*)&ks[jg][0];
      const float4* k1r = (const float4*)&ks[jg + 8][0];
      const float4* k2r = (const float4*)&ks[jg + 16][0];
      const float4* k3r = (const float4*)&ks[jg + 24][0];
#pragma unroll
      for (int d4 = 0; d4 < 32; d4++) {
        float4 q4 = qr[d4];
        float4 a = k0r[d4], b = k1r[d4], c = k2r[d4], d = k3r[d4];
        sc0 += q4.x * a.x + q4.y * a.y + q4.z * a.z + q4.w * a.w;
        sc1 += q4.x * b.x + q4.y * b.y + q4.z * b.z + q4.w * b.w;
        sc2 += q4.x * c.x + q4.y * c.y + q4.z * c.z + q4.w * c.w;
        sc3 += q4.x * d.x + q4.y * d.y + q4.z * d.z + q4.w * d.w;
      }
    }
    float sc[4] = {sc0, sc1, sc2, sc3};
    int qrow = qb * 32 + r;
    float mx = -3.0e38f;
#pragma unroll
    for (int ii = 0; ii < 4; ii++) {
      int kcol = kc * 32 + jg + 8 * ii;
      sc[ii] = (kcol <= qrow) ? sc[ii] * scale : -3.0e38f;
      mx = fmaxf(mx, sc[ii]);
    }
    red[r][jg] = mx;
    __syncthreads();
    if (tid < 32) {
      float m2 = mrow[tid];
#pragma unroll
      for (int j = 0; j < 8; j++) m2 = fmaxf(m2, red[tid][j]);
      arow[tid] = expf(mrow[tid] - m2);
      mrow[tid] = m2;
    }
    __syncthreads();
    float m2 = mrow[r], psum = 0.f;
#pragma unroll
    for (int ii = 0; ii < 4; ii++) {
      float p = expf(sc[ii] - m2);
      ps[r][jg + 8 * ii] = p;
      psum += p;
    }
    red[r][jg] = psum;
    __syncthreads();
    if (tid < 32) {
      float s2 = 0.f;
#pragma unroll
      for (int j = 0; j < 8; j++) s2 += red[tid][j];
      lrow[tid] = lrow[tid] * arow[tid] + s2;
    }
    float al = arow[r];
#pragma unroll
    for (int i = 0; i < 16; i++) o[i] *= al;
    for (int j = 0; j < 32; j++) {
      float p = ps[r][j];
      const float4* vr = (const float4*)&vs[j][c0];
      float4 v0 = vr[0], v1 = vr[1], v2 = vr[2], v3 = vr[3];
      o[0] += p * v0.x; o[1] += p * v0.y; o[2] += p * v0.z; o[3] += p * v0.w;
      o[4] += p * v1.x; o[5] += p * v1.y; o[6] += p * v1.z; o[7] += p * v1.w;
      o[8] += p * v2.x; o[9] += p * v2.y; o[10] += p * v2.z; o[11] += p * v2.w;
      o[12] += p * v3.x; o[13] += p * v3.y; o[14] += p * v3.z; o[15] += p * v3.w;
    }
    __syncthreads();
  }
  float li = 1.0f / lrow[r];
  size_t ob = (size_t)(qb * 32 + r) * H_ + hd * 128 + c0;
#pragma unroll
  for (int i = 0; i < 16; i++) attnh[ob + i] = (h16)(o[i] * li);
}

// ---------------------------------------------------------------------------
// Router: fp32 logits, softmax, top-4 (tie -> lower index), sigmoid(sgate).
// One wave per token.
// ---------------------------------------------------------------------------
__global__ __launch_bounds__(256) void router_kernel(
    const float* __restrict__ h2f, const float* __restrict__ gate_w,
    const float* __restrict__ sgate_w, float* __restrict__ logits_out,
    int* __restrict__ sel4, float* __restrict__ rw4, float* __restrict__ sgs) {
  int token = blockIdx.x * 4 + (threadIdx.x >> 6);
  int lane = threadIdx.x & 63;
  const float* hrow = h2f + (size_t)token * H_;
  float acc[8] = {0, 0, 0, 0, 0, 0, 0, 0};
  float accs = 0.f;
  for (int i = lane; i < H_; i += 64) {
    float hv = hrow[i];
    const float* g = gate_w + (size_t)i * E_;
#pragma unroll
    for (int e = 0; e < 8; e++) acc[e] += hv * g[e];
    accs += hv * sgate_w[i];
  }
#pragma unroll
  for (int e = 0; e < 8; e++)
    for (int m = 32; m > 0; m >>= 1) acc[e] += __shfl_xor(acc[e], m);
  for (int m = 32; m > 0; m >>= 1) accs += __shfl_xor(accs, m);
  if (lane == 0) {
    float mx = acc[0];
#pragma unroll
    for (int e = 1; e < 8; e++) mx = fmaxf(mx, acc[e]);
    float p[8], sum = 0.f;
#pragma unroll
    for (int e = 0; e < 8; e++) { p[e] = expf(acc[e] - mx); sum += p[e]; }
    float isum = 1.f / sum;
#pragma unroll
    for (int e = 0; e < 8; e++) {
      p[e] *= isum;
      logits_out[(size_t)token * E_ + e] = acc[e];
    }
    bool used[8] = {false, false, false, false, false, false, false, false};
    for (int k = 0; k < TOPK_; k++) {
      int best = -1; float bv = -1.f;
      for (int e = 0; e < 8; e++)
        if (!used[e] && p[e] > bv) { bv = p[e]; best = e; }
      used[best] = true;
      sel4[token * TOPK_ + k] = best;
      rw4[token * TOPK_ + k] = bv;
    }
    sgs[token] = 1.f / (1.f + expf(-accs));
  }
}

__global__ __launch_bounds__(256) void count_kernel(const int* __restrict__ sel4,
                                                    int* __restrict__ cnt) {
  int s = blockIdx.x * 256 + threadIdx.x;
  if (s >= S_) return;
#pragma unroll
  for (int j = 0; j < TOPK_; j++) atomicAdd(&cnt[sel4[s * TOPK_ + j]], 1);
}

__global__ void offsets_kernel(const int* __restrict__ cnt, int* __restrict__ offs,
                               int* __restrict__ cursor) {
  if (threadIdx.x == 0 && blockIdx.x == 0) {
    int a = 0;
    for (int e = 0; e < E_; e++) { offs[e] = a; cursor[e] = a; a += cnt[e]; }
  }
}

__global__ __launch_bounds__(256) void fill_kernel(
    const int* __restrict__ sel4, const float* __restrict__ rw4,
    int* __restrict__ cursor, int* __restrict__ rowidx, float* __restrict__ roww) {
  int s = blockIdx.x * 256 + threadIdx.x;
  if (s >= S_) return;
  for (int j = 0; j < TOPK_; j++) {
    int e = sel4[s * TOPK_ + j];
    int pos = atomicAdd(&cursor[e], 1);
    rowidx[pos] = s;
    roww[pos] = rw4[s * TOPK_ + j];
  }
}

// ---------------------------------------------------------------------------
// silu(gate)*up, fp16 in/out. gu row = [gate (W) | up (W)].
// ---------------------------------------------------------------------------
template <int W>
__global__ __launch_bounds__(256) void silu_mul_kernel(
    const h16* __restrict__ gu, h16* __restrict__ act, long long total) {
  long long idx = (long long)blockIdx.x * 256 + threadIdx.x;
  if (idx >= total) return;
  int row = (int)(idx / W);
  int col = (int)(idx % W);
  float g = (float)gu[(size_t)row * (2 * W) + col];
  float u = (float)gu[(size_t)row * (2 * W) + W + col];
  float a = g / (1.f + expf(-g)) * u;
  act[idx] = (h16)a;
}

__global__ __launch_bounds__(256) void final_add_kernel(
    const float4* __restrict__ x2, const float4* __restrict__ acc,
    float4* __restrict__ out) {
  int i = blockIdx.x * 256 + threadIdx.x;
  float4 a = x2[i], b = acc[i];
  float4 r;
  r.x = a.x + b.x; r.y = a.y + b.y; r.z = a.z + b.z; r.w = a.w + b.w;
  out[i] = r;
}

// ---------------------------------------------------------------------------
extern "C" void kernel_launch(void* const* d_in, const int* in_sizes, int n_in,
                              void* d_out, int out_size, void* d_ws, size_t ws_size,
                              hipStream_t stream) {
  const float* x      = (const float*)d_in[0];
  const float* ln1    = (const float*)d_in[1];
  const float* ln2    = (const float*)d_in[2];
  const float* wq     = (const float*)d_in[3];
  const float* bq     = (const float*)d_in[4];
  const float* wk     = (const float*)d_in[5];
  const float* bk     = (const float*)d_in[6];
  const float* wv     = (const float*)d_in[7];
  const float* bv     = (const float*)d_in[8];
  const float* wo     = (const float*)d_in[9];
  const float* gatew  = (const float*)d_in[10];
  const float* eg     = (const float*)d_in[11];
  const float* eu     = (const float*)d_in[12];
  const float* ed     = (const float*)d_in[13];
  const float* sg     = (const float*)d_in[14];
  const float* su     = (const float*)d_in[15];
  const float* sd     = (const float*)d_in[16];
  const float* sgate  = (const float*)d_in[17];
  float* out = (float*)d_out;

  // ---- workspace layout (~334 MB) ----
  char* w = (char*)d_ws;
  size_t off = 0;
  auto alloc = [&](size_t n) {
    char* p = w + off;
    off += (n + 255) & ~(size_t)255;
    return p;
  };
  h16* h1h     = (h16*)alloc((size_t)S_ * H_ * 2);
  float* qkv   = (float*)alloc((size_t)S_ * NQKV_ * 4);
  h16* attnh   = (h16*)alloc((size_t)S_ * H_ * 2);
  float* x2    = (float*)alloc((size_t)S_ * H_ * 4);
  h16* h2h     = (h16*)alloc((size_t)S_ * H_ * 2);
  float* h2f   = (float*)alloc((size_t)S_ * H_ * 4);
  float* sgs   = (float*)alloc((size_t)S_ * 4);
  int* sel4    = (int*)alloc((size_t)S_ * TOPK_ * 4);
  float* rw4   = (float*)alloc((size_t)S_ * TOPK_ * 4);
  int* cnt     = (int*)alloc(96);  // cnt[8] | offs[8] | cursor[8]
  int* offs    = cnt + 8;
  int* cursor  = cnt + 16;
  int* rowidx  = (int*)alloc(8192 * 4);
  float* roww  = (float*)alloc(8192 * 4);
  float* moeac = (float*)alloc((size_t)S_ * H_ * 4);
  char* WAR    = alloc(138412032);  // weight arena (max: eguT+edT)
  char* GAR    = alloc(69206016);   // gate-up / act arena

  h16* qkvT = (h16*)WAR;                                  // 6144 x 2048
  h16* woT  = (h16*)(WAR + (size_t)NQKV_ * H_ * 2);       // 2048 x 2048
  h16* sguT = (h16*)WAR;                                  // 11264 x 2048
  h16* sdT  = (h16*)(WAR + (size_t)2 * IS_ * H_ * 2);     // 2048 x 5632
  h16* eguT = (h16*)WAR;                                  // 8 x 2816 x 2048
  h16* edT  = (h16*)(WAR + (size_t)E_ * 2 * IE_ * H_ * 2);// 8 x 2048 x 1408
  h16* gu_s = (h16*)GAR;
  h16* act_s = (h16*)(GAR + (size_t)S_ * 2 * IS_ * 2);
  h16* gu_e = (h16*)GAR;
  h16* act_e = (h16*)(GAR + (size_t)8192 * 2 * IE_ * 2);

  // ---- init ----
  hipMemsetAsync(cnt, 0, 32, stream);
  hipMemsetAsync(moeac, 0, (size_t)S_ * H_ * 4, stream);

  // ---- stage A weights: qkv + wo ----
  transpose_kernel<<<dim3(64, 64, 1), 256, 0, stream>>>(wq, qkvT, H_, H_, 0, 0);
  transpose_kernel<<<dim3(64, 64, 1), 256, 0, stream>>>(wk, qkvT + (size_t)H_ * H_, H_, H_, 0, 0);
  transpose_kernel<<<dim3(64, 64, 1), 256, 0, stream>>>(wv, qkvT + (size_t)2 * H_ * H_, H_, H_, 0, 0);
  transpose_kernel<<<dim3(64, 64, 1), 256, 0, stream>>>(wo, woT, H_, H_, 0, 0);

  // ---- attention path ----
  rmsnorm_kernel<false><<<S_, 256, 0, stream>>>(x, ln1, h1h, nullptr);
  gemm_kernel<0, false><<<dim3(16, 48), 256, 0, stream>>>(
      h1h, qkvT, qkv, S_, NQKV_, H_, nullptr, nullptr);
  rope_kernel<<<(S_ * NH_ * 64) / 256, 256, 0, stream>>>(qkv, bq, bk, bv);
  attn_kernel<<<dim3(64, NH_), 256, 0, stream>>>(qkv, attnh);
  gemm_kernel<0, true><<<dim3(16, 16), 256, 0, stream>>>(
      attnh, woT, x2, S_, H_, H_, x, nullptr);

  // ---- router ----
  rmsnorm_kernel<true><<<S_, 256, 0, stream>>>(x2, ln2, h2h, h2f);
  router_kernel<<<S_ / 4, 256, 0, stream>>>(h2f, gatew, sgate,
                                            out + (size_t)S_ * H_, sel4, rw4, sgs);
  count_kernel<<<S_ / 256, 256, 0, stream>>>(sel4, cnt);
  offsets_kernel<<<1, 64, 0, stream>>>(cnt, offs, cursor);
  fill_kernel<<<S_ / 256, 256, 0, stream>>>(sel4, rw4, cursor, rowidx, roww);

  // ---- shared expert ----
  transpose_kernel<<<dim3(176, 64, 1), 256, 0, stream>>>(sg, sguT, H_, IS_, 0, 0);
  transpose_kernel<<<dim3(176, 64, 1), 256, 0, stream>>>(su, sguT + (size_t)IS_ * H_, H_, IS_, 0, 0);
  transpose_kernel<<<dim3(64, 176, 1), 256, 0, stream>>>(sd, sdT, IS_, H_, 0, 0);
  gemm_kernel<1, false><<<dim3(16, 88), 256, 0, stream>>>(
      h2h, sguT, gu_s, S_, 2 * IS_, H_, nullptr, nullptr);
  {
    long long tot = (long long)S_ * IS_;
    silu_mul_kernel<IS_><<<(unsigned)((tot + 255) / 256), 256, 0, stream>>>(gu_s, act_s, tot);
  }
  gemm_kernel<2, false><<<dim3(16, 16), 256, 0, stream>>>(
      act_s, sdT, moeac, S_, H_, IS_, nullptr, sgs);

  // ---- routed experts ----
  transpose_kernel<<<dim3(44, 64, 8), 256, 0, stream>>>(
      eg, eguT, H_, IE_, (long long)H_ * IE_, (long long)2 * IE_ * H_);
  transpose_kernel<<<dim3(44, 64, 8), 256, 0, stream>>>(
      eu, eguT + (size_t)IE_ * H_, H_, IE_, (long long)H_ * IE_, (long long)2 * IE_ * H_);
  transpose_kernel<<<dim3(64, 44, 8), 256, 0, stream>>>(
      ed, edT, IE_, H_, (long long)IE_ * H_, (long long)H_ * IE_);
  moe_gemm_kernel<0><<<dim3(16, 22, 8), 256, 0, stream>>>(
      h2h, eguT, gu_e, offs, cnt, rowidx, roww, 2 * IE_, H_);
  {
    long long tot = (long long)8192 * IE_;
    silu_mul_kernel<IE_><<<(unsigned)((tot + 255) / 256), 256, 0, stream>>>(gu_e, act_e, tot);
  }
  moe_gemm_kernel<1><<<dim3(16, 16, 8), 256, 0, stream>>>(
      act_e, edT, moeac, offs, cnt, rowidx, roww, H_, IE_);

  // ---- output ----
  final_add_kernel<<<(S_ * H_) / 1024, 256, 0, stream>>>(
      (const float4*)x2, (const float4*)moeac, (float4*)out);
}

// Round 2
// 1710.340 us; speedup vs baseline: 1.4726x; 1.4726x over previous
//
#include <hip/hip_runtime.h>
#include <math.h>

// ---------------------------------------------------------------------------
// Qwen2MoE decoder layer, MI355X (gfx950).
// fp16-staged MFMA GEMMs (f32 accum), MFMA flash attention, fp32 router/top-k.
// ---------------------------------------------------------------------------

typedef _Float16 h16;
typedef _Float16 half8 __attribute__((ext_vector_type(8)));
typedef float f32x4 __attribute__((ext_vector_type(4)));

#define S_ 2048
#define H_ 2048
#define NH_ 16
#define D_ 128
#define E_ 8
#define TOPK_ 4
#define IE_ 1408
#define IS_ 5632
#define NQKV_ 6144

// ---------------------------------------------------------------------------
// Transpose fp32 (R x C) -> fp16 (C x R), batched over z.
// ---------------------------------------------------------------------------
__global__ __launch_bounds__(256) void transpose_kernel(
    const float* __restrict__ in, h16* __restrict__ out,
    int R, int C, long long inZ, long long outZ) {
  in  += (size_t)blockIdx.z * inZ;
  out += (size_t)blockIdx.z * outZ;
  __shared__ float tile[32][33];
  int c0 = blockIdx.x * 32, r0 = blockIdx.y * 32;
  int tx = threadIdx.x & 31, ty = threadIdx.x >> 5;  // 32 x 8
#pragma unroll
  for (int i = 0; i < 4; i++)
    tile[ty + 8 * i][tx] = in[(size_t)(r0 + ty + 8 * i) * C + c0 + tx];
  __syncthreads();
#pragma unroll
  for (int i = 0; i < 4; i++)
    out[(size_t)(c0 + ty + 8 * i) * R + r0 + tx] = (h16)tile[tx][ty + 8 * i];
}

// ---------------------------------------------------------------------------
// RMSNorm: one block per row. Writes fp16 (and optionally fp32).
// ---------------------------------------------------------------------------
template <bool F32OUT>
__global__ __launch_bounds__(256) void rmsnorm_kernel(
    const float* __restrict__ x, const float* __restrict__ w,
    h16* __restrict__ outh, float* __restrict__ outf) {
  int row = blockIdx.x;
  const float* xr = x + (size_t)row * H_;
  float ss = 0.f;
  for (int i = threadIdx.x; i < H_; i += 256) { float v = xr[i]; ss += v * v; }
  for (int o = 32; o > 0; o >>= 1) ss += __shfl_down(ss, o);
  __shared__ float sred[4];
  if ((threadIdx.x & 63) == 0) sred[threadIdx.x >> 6] = ss;
  __syncthreads();
  float tot = sred[0] + sred[1] + sred[2] + sred[3];
  float r = rsqrtf(tot * (1.0f / H_) + 1e-6f);
  for (int i = threadIdx.x; i < H_; i += 256) {
    float hv = xr[i] * r * w[i];
    outh[(size_t)row * H_ + i] = (h16)hv;
    if (F32OUT) outf[(size_t)row * H_ + i] = hv;
  }
}

// ---------------------------------------------------------------------------
// Generic MFMA GEMM: C[M,N] = A[M,K] * Bt[N,K]^T. A,Bt fp16, accum fp32.
// BM=BN=128, BK=32, 256 threads (4 waves, each 64x64 = 4x4 MFMA 16x16x32).
// STORE: 0 = fp32 store, 1 = fp16 store, 2 = atomicAdd(rowscale[row]*val).
// ---------------------------------------------------------------------------
template <int STORE, bool RESID>
__global__ __launch_bounds__(256, 2) void gemm_kernel(
    const h16* __restrict__ A, const h16* __restrict__ Bt, void* __restrict__ Cv,
    int M, int N, int K,
    const float* __restrict__ resid, const float* __restrict__ rowscale) {
  __shared__ __align__(16) h16 As[128][40];
  __shared__ __align__(16) h16 Bs[128][40];
  const int tid = threadIdx.x;
  const int wave = tid >> 6, lane = tid & 63;
  const int wm = wave >> 1, wn = wave & 1;
  const int quad = lane >> 4, l16 = lane & 15;
  const int row0 = blockIdx.x * 128, col0 = blockIdx.y * 128;

  f32x4 acc[4][4];
#pragma unroll
  for (int i = 0; i < 4; i++)
#pragma unroll
    for (int j = 0; j < 4; j++) acc[i][j] = (f32x4){0.f, 0.f, 0.f, 0.f};

  const h16* Ablk = A + (size_t)row0 * K;
  const h16* Bblk = Bt + (size_t)col0 * K;
  const int ldr0 = tid >> 2;         // staging row (chunk 0)
  const int ldk = (tid & 3) * 8;     // 8 fp16 = 16B per chunk

  for (int k0 = 0; k0 < K; k0 += 32) {
#pragma unroll
    for (int i = 0; i < 2; i++) {
      int row = ldr0 + i * 64;
      uint4 av = *(const uint4*)(Ablk + (size_t)row * K + k0 + ldk);
      *(uint4*)(&As[row][ldk]) = av;
      uint4 bv = *(const uint4*)(Bblk + (size_t)row * K + k0 + ldk);
      *(uint4*)(&Bs[row][ldk]) = bv;
    }
    __syncthreads();
    half8 af[4], bfv[4];
#pragma unroll
    for (int mi = 0; mi < 4; mi++)
      af[mi] = *(const half8*)(&As[wm * 64 + mi * 16 + l16][quad * 8]);
#pragma unroll
    for (int ni = 0; ni < 4; ni++)
      bfv[ni] = *(const half8*)(&Bs[wn * 64 + ni * 16 + l16][quad * 8]);
#pragma unroll
    for (int mi = 0; mi < 4; mi++)
#pragma unroll
      for (int ni = 0; ni < 4; ni++)
        acc[mi][ni] = __builtin_amdgcn_mfma_f32_16x16x32_f16(af[mi], bfv[ni], acc[mi][ni], 0, 0, 0);
    __syncthreads();
  }

#pragma unroll
  for (int mi = 0; mi < 4; mi++) {
#pragma unroll
    for (int ni = 0; ni < 4; ni++) {
      int col = col0 + wn * 64 + ni * 16 + l16;
#pragma unroll
      for (int r = 0; r < 4; r++) {
        int row = row0 + wm * 64 + mi * 16 + quad * 4 + r;
        float val = acc[mi][ni][r];
        if (RESID) val += resid[(size_t)row * N + col];
        if (STORE == 0) ((float*)Cv)[(size_t)row * N + col] = val;
        else if (STORE == 1) ((h16*)Cv)[(size_t)row * N + col] = (h16)val;
        else atomicAdd(&((float*)Cv)[(size_t)row * N + col], rowscale[row] * val);
      }
    }
  }
}

// ---------------------------------------------------------------------------
// MoE GEMM. z = expert. PHASE 0: gathered A rows (rowidx) -> fp16 gu slots.
// PHASE 1: linear slot A rows -> atomicAdd roww[slot]*val into moe_acc[token].
// ---------------------------------------------------------------------------
template <int PHASE>
__global__ __launch_bounds__(256, 2) void moe_gemm_kernel(
    const h16* __restrict__ A, const h16* __restrict__ BtAll, void* __restrict__ Cv,
    const int* __restrict__ offs, const int* __restrict__ cnt,
    const int* __restrict__ rowidx, const float* __restrict__ roww,
    int N, int K) {
  const int e = blockIdx.z;
  const int Me = cnt[e], offe = offs[e];
  const int row0 = blockIdx.x * 128;
  if (row0 >= Me) return;
  const int col0 = blockIdx.y * 128;
  const h16* Bt = BtAll + (size_t)e * N * K;

  __shared__ __align__(16) h16 As[128][40];
  __shared__ __align__(16) h16 Bs[128][40];
  const int tid = threadIdx.x;
  const int wave = tid >> 6, lane = tid & 63;
  const int wm = wave >> 1, wn = wave & 1;
  const int quad = lane >> 4, l16 = lane & 15;

  f32x4 acc[4][4];
#pragma unroll
  for (int i = 0; i < 4; i++)
#pragma unroll
    for (int j = 0; j < 4; j++) acc[i][j] = (f32x4){0.f, 0.f, 0.f, 0.f};

  const int ldr0 = tid >> 2;
  const int ldk = (tid & 3) * 8;
  size_t abase[2]; bool aval[2];
#pragma unroll
  for (int i = 0; i < 2; i++) {
    int row = ldr0 + i * 64;
    aval[i] = (row0 + row) < Me;
    int slot = offe + row0 + row;
    int ar = aval[i] ? (PHASE == 0 ? rowidx[slot] : slot) : 0;
    abase[i] = (size_t)ar * K;
  }

  for (int k0 = 0; k0 < K; k0 += 32) {
#pragma unroll
    for (int i = 0; i < 2; i++) {
      int row = ldr0 + i * 64;
      uint4 av = {0, 0, 0, 0};
      if (aval[i]) av = *(const uint4*)(A + abase[i] + k0 + ldk);
      *(uint4*)(&As[row][ldk]) = av;
      uint4 bv = *(const uint4*)(Bt + (size_t)(col0 + row) * K + k0 + ldk);
      *(uint4*)(&Bs[row][ldk]) = bv;
    }
    __syncthreads();
    half8 af[4], bfv[4];
#pragma unroll
    for (int mi = 0; mi < 4; mi++)
      af[mi] = *(const half8*)(&As[wm * 64 + mi * 16 + l16][quad * 8]);
#pragma unroll
    for (int ni = 0; ni < 4; ni++)
      bfv[ni] = *(const half8*)(&Bs[wn * 64 + ni * 16 + l16][quad * 8]);
#pragma unroll
    for (int mi = 0; mi < 4; mi++)
#pragma unroll
      for (int ni = 0; ni < 4; ni++)
        acc[mi][ni] = __builtin_amdgcn_mfma_f32_16x16x32_f16(af[mi], bfv[ni], acc[mi][ni], 0, 0, 0);
    __syncthreads();
  }

#pragma unroll
  for (int mi = 0; mi < 4; mi++) {
#pragma unroll
    for (int ni = 0; ni < 4; ni++) {
      int col = col0 + wn * 64 + ni * 16 + l16;
#pragma unroll
      for (int r = 0; r < 4; r++) {
        int lrow = wm * 64 + mi * 16 + quad * 4 + r;
        if (row0 + lrow < Me) {
          int slot = offe + row0 + lrow;
          float val = acc[mi][ni][r];
          if (PHASE == 0) {
            ((h16*)Cv)[(size_t)slot * N + col] = (h16)val;
          } else {
            int token = rowidx[slot];
            atomicAdd(&((float*)Cv)[(size_t)token * N + col], roww[slot] * val);
          }
        }
      }
    }
  }
}

// ---------------------------------------------------------------------------
// RoPE + bias: qkv fp32 -> Qh, Kh fp16 [s][h*128+d]. One thread per (s,h,d<64).
// ---------------------------------------------------------------------------
__global__ __launch_bounds__(256) void rope_kernel(
    const float* __restrict__ qkv, const float* __restrict__ bq,
    const float* __restrict__ bk, h16* __restrict__ Qh, h16* __restrict__ Kh) {
  int idx = blockIdx.x * 256 + threadIdx.x;
  int d = idx & 63;
  int h = (idx >> 6) & (NH_ - 1);
  int s = idx >> 10;
  float inv = powf(1.0e6f, -(float)d * (1.0f / 64.0f));
  float ang = (float)s * inv;
  float sn, c;
  sincosf(ang, &sn, &c);
  const float* base = qkv + (size_t)s * NQKV_;
  int iq = h * 128 + d;
  float q1 = base[iq] + bq[iq];
  float q2 = base[iq + 64] + bq[iq + 64];
  Qh[(size_t)s * H_ + iq] = (h16)(q1 * c - q2 * sn);
  Qh[(size_t)s * H_ + iq + 64] = (h16)(q2 * c + q1 * sn);
  float k1 = base[2048 + iq] + bk[iq];
  float k2 = base[2048 + iq + 64] + bk[iq + 64];
  Kh[(size_t)s * H_ + iq] = (h16)(k1 * c - k2 * sn);
  Kh[(size_t)s * H_ + iq + 64] = (h16)(k2 * c + k1 * sn);
}

// ---------------------------------------------------------------------------
// V transpose + bias: qkv fp32 -> Vt fp16 [h][d][s].
// ---------------------------------------------------------------------------
__global__ __launch_bounds__(256) void vtrans_kernel(
    const float* __restrict__ qkv, const float* __restrict__ bv,
    h16* __restrict__ Vt) {
  int h = blockIdx.z;
  __shared__ float tile[32][33];
  int c0 = blockIdx.x * 32;  // d
  int r0 = blockIdx.y * 32;  // s
  int tx = threadIdx.x & 31, ty = threadIdx.x >> 5;
#pragma unroll
  for (int i = 0; i < 4; i++)
    tile[ty + 8 * i][tx] =
        qkv[(size_t)(r0 + ty + 8 * i) * NQKV_ + 4096 + h * 128 + c0 + tx] +
        bv[h * 128 + c0 + tx];
  __syncthreads();
#pragma unroll
  for (int i = 0; i < 4; i++)
    Vt[(size_t)h * D_ * S_ + (size_t)(c0 + ty + 8 * i) * S_ + r0 + tx] =
        (h16)tile[tx][ty + 8 * i];
}

// ---------------------------------------------------------------------------
// MFMA flash attention, causal. Block = 64 q-rows of one head; 4 waves, each
// wave owns 16 q-rows. K-tile = 64. Q/K fragments direct from global (fp16,
// row-major [s][d]); V fragments direct from Vt [h][d][s]. P goes through a
// small per-wave LDS tile for the C-layout -> A-layout transform.
// ---------------------------------------------------------------------------
__global__ __launch_bounds__(256, 4) void attn_mfma_kernel(
    const h16* __restrict__ Qh, const h16* __restrict__ Kh,
    const h16* __restrict__ Vt, h16* __restrict__ attnh) {
  const int head = blockIdx.x & 15;
  const int qb = 31 - (blockIdx.x >> 4);  // heavy blocks first
  const int wave = threadIdx.x >> 6, lane = threadIdx.x & 63;
  const int quad = lane >> 4, l16 = lane & 15;
  const int q0 = qb * 64 + wave * 16;

  __shared__ __align__(16) h16 Plds[4][16][72];

  half8 qf[4];
#pragma unroll
  for (int kk = 0; kk < 4; kk++)
    qf[kk] = *(const half8*)&Qh[(size_t)(q0 + l16) * H_ + head * D_ + kk * 32 + quad * 8];

  f32x4 o[8];
#pragma unroll
  for (int i = 0; i < 8; i++) o[i] = (f32x4){0.f, 0.f, 0.f, 0.f};
  float m_i[4], l_i[4];
#pragma unroll
  for (int r = 0; r < 4; r++) { m_i[r] = -3.0e38f; l_i[r] = 0.f; }

  const float scale = 0.08838834764831845f;  // 1/sqrt(128)
  const h16* Kbase = Kh + head * D_;
  const h16* Vbase = Vt + (size_t)head * D_ * S_;

  for (int kc = 0; kc <= qb; kc++) {
    const int kb = kc * 64;
    f32x4 s[4];
#pragma unroll
    for (int ni = 0; ni < 4; ni++) s[ni] = (f32x4){0.f, 0.f, 0.f, 0.f};
#pragma unroll
    for (int ni = 0; ni < 4; ni++) {
#pragma unroll
      for (int kk = 0; kk < 4; kk++) {
        half8 bf = *(const half8*)&Kbase[(size_t)(kb + ni * 16 + l16) * H_ + kk * 32 + quad * 8];
        s[ni] = __builtin_amdgcn_mfma_f32_16x16x32_f16(qf[kk], bf, s[ni], 0, 0, 0);
      }
    }
    // scale + causal mask (mask only needed on diagonal tile)
    if (kc == qb) {
#pragma unroll
      for (int r = 0; r < 4; r++) {
        int row = q0 + quad * 4 + r;
#pragma unroll
        for (int ni = 0; ni < 4; ni++) {
          int col = kb + ni * 16 + l16;
          s[ni][r] = (col <= row) ? s[ni][r] * scale : -3.0e38f;
        }
      }
    } else {
#pragma unroll
      for (int ni = 0; ni < 4; ni++)
#pragma unroll
        for (int r = 0; r < 4; r++) s[ni][r] *= scale;
    }
    // online softmax: row stats across the 16 lanes of each quad group
    float alpha[4];
#pragma unroll
    for (int r = 0; r < 4; r++) {
      float mx = fmaxf(fmaxf(s[0][r], s[1][r]), fmaxf(s[2][r], s[3][r]));
      mx = fmaxf(mx, __shfl_xor(mx, 1));
      mx = fmaxf(mx, __shfl_xor(mx, 2));
      mx = fmaxf(mx, __shfl_xor(mx, 4));
      mx = fmaxf(mx, __shfl_xor(mx, 8));
      float mn = fmaxf(m_i[r], mx);
      alpha[r] = __expf(m_i[r] - mn);
      m_i[r] = mn;
    }
    float rsum[4] = {0.f, 0.f, 0.f, 0.f};
#pragma unroll
    for (int ni = 0; ni < 4; ni++) {
#pragma unroll
      for (int r = 0; r < 4; r++) {
        float p = __expf(s[ni][r] - m_i[r]);
        s[ni][r] = p;
        rsum[r] += p;
      }
    }
#pragma unroll
    for (int r = 0; r < 4; r++) {
      float t = rsum[r];
      t += __shfl_xor(t, 1);
      t += __shfl_xor(t, 2);
      t += __shfl_xor(t, 4);
      t += __shfl_xor(t, 8);
      l_i[r] = l_i[r] * alpha[r] + t;
    }
    // P (C-layout) -> LDS -> A-layout fragments
#pragma unroll
    for (int ni = 0; ni < 4; ni++)
#pragma unroll
      for (int r = 0; r < 4; r++)
        Plds[wave][quad * 4 + r][ni * 16 + l16] = (h16)s[ni][r];
    // rescale O
#pragma unroll
    for (int dt = 0; dt < 8; dt++)
#pragma unroll
      for (int r = 0; r < 4; r++) o[dt][r] *= alpha[r];
    half8 pf[2];
#pragma unroll
    for (int kk = 0; kk < 2; kk++)
      pf[kk] = *(const half8*)&Plds[wave][l16][kk * 32 + quad * 8];
#pragma unroll
    for (int dt = 0; dt < 8; dt++) {
#pragma unroll
      for (int kk = 0; kk < 2; kk++) {
        half8 vf = *(const half8*)&Vbase[(size_t)(dt * 16 + l16) * S_ + kb + kk * 32 + quad * 8];
        o[dt] = __builtin_amdgcn_mfma_f32_16x16x32_f16(pf[kk], vf, o[dt], 0, 0, 0);
      }
    }
  }
#pragma unroll
  for (int r = 0; r < 4; r++) {
    float inv = 1.0f / l_i[r];
    size_t rowb = (size_t)(q0 + quad * 4 + r) * H_ + head * D_;
#pragma unroll
    for (int dt = 0; dt < 8; dt++)
      attnh[rowb + dt * 16 + l16] = (h16)(o[dt][r] * inv);
  }
}

// ---------------------------------------------------------------------------
// Router: fp32 logits, softmax, top-4 (tie -> lower index), sigmoid(sgate).
// One wave per token.
// ---------------------------------------------------------------------------
__global__ __launch_bounds__(256) void router_kernel(
    const float* __restrict__ h2f, const float* __restrict__ gate_w,
    const float* __restrict__ sgate_w, float* __restrict__ logits_out,
    int* __restrict__ sel4, float* __restrict__ rw4, float* __restrict__ sgs) {
  int token = blockIdx.x * 4 + (threadIdx.x >> 6);
  int lane = threadIdx.x & 63;
  const float* hrow = h2f + (size_t)token * H_;
  float acc[8] = {0, 0, 0, 0, 0, 0, 0, 0};
  float accs = 0.f;
  for (int i = lane; i < H_; i += 64) {
    float hv = hrow[i];
    const float* g = gate_w + (size_t)i * E_;
#pragma unroll
    for (int e = 0; e < 8; e++) acc[e] += hv * g[e];
    accs += hv * sgate_w[i];
  }
#pragma unroll
  for (int e = 0; e < 8; e++)
    for (int m = 32; m > 0; m >>= 1) acc[e] += __shfl_xor(acc[e], m);
  for (int m = 32; m > 0; m >>= 1) accs += __shfl_xor(accs, m);
  if (lane == 0) {
    float mx = acc[0];
#pragma unroll
    for (int e = 1; e < 8; e++) mx = fmaxf(mx, acc[e]);
    float p[8], sum = 0.f;
#pragma unroll
    for (int e = 0; e < 8; e++) { p[e] = expf(acc[e] - mx); sum += p[e]; }
    float isum = 1.f / sum;
#pragma unroll
    for (int e = 0; e < 8; e++) {
      p[e] *= isum;
      logits_out[(size_t)token * E_ + e] = acc[e];
    }
    bool used[8] = {false, false, false, false, false, false, false, false};
    for (int k = 0; k < TOPK_; k++) {
      int best = -1; float bv = -1.f;
      for (int e = 0; e < 8; e++)
        if (!used[e] && p[e] > bv) { bv = p[e]; best = e; }
      used[best] = true;
      sel4[token * TOPK_ + k] = best;
      rw4[token * TOPK_ + k] = bv;
    }
    sgs[token] = 1.f / (1.f + expf(-accs));
  }
}

__global__ __launch_bounds__(256) void count_kernel(const int* __restrict__ sel4,
                                                    int* __restrict__ cnt) {
  int s = blockIdx.x * 256 + threadIdx.x;
  if (s >= S_) return;
#pragma unroll
  for (int j = 0; j < TOPK_; j++) atomicAdd(&cnt[sel4[s * TOPK_ + j]], 1);
}

__global__ void offsets_kernel(const int* __restrict__ cnt, int* __restrict__ offs,
                               int* __restrict__ cursor) {
  if (threadIdx.x == 0 && blockIdx.x == 0) {
    int a = 0;
    for (int e = 0; e < E_; e++) { offs[e] = a; cursor[e] = a; a += cnt[e]; }
  }
}

__global__ __launch_bounds__(256) void fill_kernel(
    const int* __restrict__ sel4, const float* __restrict__ rw4,
    int* __restrict__ cursor, int* __restrict__ rowidx, float* __restrict__ roww) {
  int s = blockIdx.x * 256 + threadIdx.x;
  if (s >= S_) return;
  for (int j = 0; j < TOPK_; j++) {
    int e = sel4[s * TOPK_ + j];
    int pos = atomicAdd(&cursor[e], 1);
    rowidx[pos] = s;
    roww[pos] = rw4[s * TOPK_ + j];
  }
}

// ---------------------------------------------------------------------------
// silu(gate)*up, fp16 in/out. gu row = [gate (W) | up (W)].
// ---------------------------------------------------------------------------
template <int W>
__global__ __launch_bounds__(256) void silu_mul_kernel(
    const h16* __restrict__ gu, h16* __restrict__ act, long long total) {
  long long idx = (long long)blockIdx.x * 256 + threadIdx.x;
  if (idx >= total) return;
  int row = (int)(idx / W);
  int col = (int)(idx % W);
  float g = (float)gu[(size_t)row * (2 * W) + col];
  float u = (float)gu[(size_t)row * (2 * W) + W + col];
  float a = g / (1.f + expf(-g)) * u;
  act[idx] = (h16)a;
}

__global__ __launch_bounds__(256) void final_add_kernel(
    const float4* __restrict__ x2, const float4* __restrict__ acc,
    float4* __restrict__ out) {
  int i = blockIdx.x * 256 + threadIdx.x;
  float4 a = x2[i], b = acc[i];
  float4 r;
  r.x = a.x + b.x; r.y = a.y + b.y; r.z = a.z + b.z; r.w = a.w + b.w;
  out[i] = r;
}

// ---------------------------------------------------------------------------
extern "C" void kernel_launch(void* const* d_in, const int* in_sizes, int n_in,
                              void* d_out, int out_size, void* d_ws, size_t ws_size,
                              hipStream_t stream) {
  const float* x      = (const float*)d_in[0];
  const float* ln1    = (const float*)d_in[1];
  const float* ln2    = (const float*)d_in[2];
  const float* wq     = (const float*)d_in[3];
  const float* bq     = (const float*)d_in[4];
  const float* wk     = (const float*)d_in[5];
  const float* bk     = (const float*)d_in[6];
  const float* wv     = (const float*)d_in[7];
  const float* bv     = (const float*)d_in[8];
  const float* wo     = (const float*)d_in[9];
  const float* gatew  = (const float*)d_in[10];
  const float* eg     = (const float*)d_in[11];
  const float* eu     = (const float*)d_in[12];
  const float* ed     = (const float*)d_in[13];
  const float* sg     = (const float*)d_in[14];
  const float* su     = (const float*)d_in[15];
  const float* sd     = (const float*)d_in[16];
  const float* sgate  = (const float*)d_in[17];
  float* out = (float*)d_out;

  // ---- workspace layout (~334 MB) ----
  char* w = (char*)d_ws;
  size_t off = 0;
  auto alloc = [&](size_t n) {
    char* p = w + off;
    off += (n + 255) & ~(size_t)255;
    return p;
  };
  h16* h1h     = (h16*)alloc((size_t)S_ * H_ * 2);
  float* qkv   = (float*)alloc((size_t)S_ * NQKV_ * 4);
  h16* attnh   = (h16*)alloc((size_t)S_ * H_ * 2);
  float* x2    = (float*)alloc((size_t)S_ * H_ * 4);
  h16* h2h     = (h16*)alloc((size_t)S_ * H_ * 2);
  float* h2f   = (float*)alloc((size_t)S_ * H_ * 4);
  float* sgs   = (float*)alloc((size_t)S_ * 4);
  int* sel4    = (int*)alloc((size_t)S_ * TOPK_ * 4);
  float* rw4   = (float*)alloc((size_t)S_ * TOPK_ * 4);
  int* cnt     = (int*)alloc(96);  // cnt[8] | offs[8] | cursor[8]
  int* offs    = cnt + 8;
  int* cursor  = cnt + 16;
  int* rowidx  = (int*)alloc(8192 * 4);
  float* roww  = (float*)alloc(8192 * 4);
  float* moeac = (float*)alloc((size_t)S_ * H_ * 4);
  char* WAR    = alloc(138412032);  // weight arena (max: eguT+edT)
  char* GAR    = alloc(69206016);   // gate-up / act arena (also Qh/Kh/Vt)

  h16* qkvT = (h16*)WAR;                                  // 6144 x 2048
  h16* woT  = (h16*)(WAR + (size_t)NQKV_ * H_ * 2);       // 2048 x 2048
  h16* sguT = (h16*)WAR;                                  // 11264 x 2048
  h16* sdT  = (h16*)(WAR + (size_t)2 * IS_ * H_ * 2);     // 2048 x 5632
  h16* eguT = (h16*)WAR;                                  // 8 x 2816 x 2048
  h16* edT  = (h16*)(WAR + (size_t)E_ * 2 * IE_ * H_ * 2);// 8 x 2048 x 1408
  h16* gu_s = (h16*)GAR;
  h16* act_s = (h16*)(GAR + (size_t)S_ * 2 * IS_ * 2);
  h16* gu_e = (h16*)GAR;
  h16* act_e = (h16*)(GAR + (size_t)8192 * 2 * IE_ * 2);
  // attention fp16 buffers live in GAR (dead before shared-expert stage)
  h16* Qh = (h16*)GAR;
  h16* Kh = (h16*)(GAR + (size_t)S_ * H_ * 2);
  h16* Vt = (h16*)(GAR + (size_t)2 * S_ * H_ * 2);

  // ---- init ----
  hipMemsetAsync(cnt, 0, 32, stream);
  hipMemsetAsync(moeac, 0, (size_t)S_ * H_ * 4, stream);

  // ---- stage A weights: qkv + wo ----
  transpose_kernel<<<dim3(64, 64, 1), 256, 0, stream>>>(wq, qkvT, H_, H_, 0, 0);
  transpose_kernel<<<dim3(64, 64, 1), 256, 0, stream>>>(wk, qkvT + (size_t)H_ * H_, H_, H_, 0, 0);
  transpose_kernel<<<dim3(64, 64, 1), 256, 0, stream>>>(wv, qkvT + (size_t)2 * H_ * H_, H_, H_, 0, 0);
  transpose_kernel<<<dim3(64, 64, 1), 256, 0, stream>>>(wo, woT, H_, H_, 0, 0);

  // ---- attention path ----
  rmsnorm_kernel<false><<<S_, 256, 0, stream>>>(x, ln1, h1h, nullptr);
  gemm_kernel<0, false><<<dim3(16, 48), 256, 0, stream>>>(
      h1h, qkvT, qkv, S_, NQKV_, H_, nullptr, nullptr);
  rope_kernel<<<(S_ * NH_ * 64) / 256, 256, 0, stream>>>(qkv, bq, bk, Qh, Kh);
  vtrans_kernel<<<dim3(4, 64, 16), 256, 0, stream>>>(qkv, bv, Vt);
  attn_mfma_kernel<<<512, 256, 0, stream>>>(Qh, Kh, Vt, attnh);
  gemm_kernel<0, true><<<dim3(16, 16), 256, 0, stream>>>(
      attnh, woT, x2, S_, H_, H_, x, nullptr);

  // ---- router ----
  rmsnorm_kernel<true><<<S_, 256, 0, stream>>>(x2, ln2, h2h, h2f);
  router_kernel<<<S_ / 4, 256, 0, stream>>>(h2f, gatew, sgate,
                                            out + (size_t)S_ * H_, sel4, rw4, sgs);
  count_kernel<<<S_ / 256, 256, 0, stream>>>(sel4, cnt);
  offsets_kernel<<<1, 64, 0, stream>>>(cnt, offs, cursor);
  fill_kernel<<<S_ / 256, 256, 0, stream>>>(sel4, rw4, cursor, rowidx, roww);

  // ---- shared expert ----
  transpose_kernel<<<dim3(176, 64, 1), 256, 0, stream>>>(sg, sguT, H_, IS_, 0, 0);
  transpose_kernel<<<dim3(176, 64, 1), 256, 0, stream>>>(su, sguT + (size_t)IS_ * H_, H_, IS_, 0, 0);
  transpose_kernel<<<dim3(64, 176, 1), 256, 0, stream>>>(sd, sdT, IS_, H_, 0, 0);
  gemm_kernel<1, false><<<dim3(16, 88), 256, 0, stream>>>(
      h2h, sguT, gu_s, S_, 2 * IS_, H_, nullptr, nullptr);
  {
    long long tot = (long long)S_ * IS_;
    silu_mul_kernel<IS_><<<(unsigned)((tot + 255) / 256), 256, 0, stream>>>(gu_s, act_s, tot);
  }
  gemm_kernel<2, false><<<dim3(16, 16), 256, 0, stream>>>(
      act_s, sdT, moeac, S_, H_, IS_, nullptr, sgs);

  // ---- routed experts ----
  transpose_kernel<<<dim3(44, 64, 8), 256, 0, stream>>>(
      eg, eguT, H_, IE_, (long long)H_ * IE_, (long long)2 * IE_ * H_);
  transpose_kernel<<<dim3(44, 64, 8), 256, 0, stream>>>(
      eu, eguT + (size_t)IE_ * H_, H_, IE_, (long long)H_ * IE_, (long long)2 * IE_ * H_);
  transpose_kernel<<<dim3(64, 44, 8), 256, 0, stream>>>(
      ed, edT, IE_, H_, (long long)IE_ * H_, (long long)H_ * IE_);
  moe_gemm_kernel<0><<<dim3(16, 22, 8), 256, 0, stream>>>(
      h2h, eguT, gu_e, offs, cnt, rowidx, roww, 2 * IE_, H_);
  {
    long long tot = (long long)8192 * IE_;
    silu_mul_kernel<IE_><<<(unsigned)((tot + 255) / 256), 256, 0, stream>>>(gu_e, act_e, tot);
  }
  moe_gemm_kernel<1><<<dim3(16, 16, 8), 256, 0, stream>>>(
      act_e, edT, moeac, offs, cnt, rowidx, roww, H_, IE_);

  // ---- output ----
  final_add_kernel<<<(S_ * H_) / 1024, 256, 0, stream>>>(
      (const float4*)x2, (const float4*)moeac, (float4*)out);
}

// Round 3
// 1614.923 us; speedup vs baseline: 1.5596x; 1.0591x over previous
//
#include <hip/hip_runtime.h>
#include <math.h>

// ---------------------------------------------------------------------------
// Qwen2MoE decoder layer, MI355X (gfx950).
// fp16-staged MFMA GEMMs (f32 accum, global_load_lds staging), MFMA flash
// attention, fp32 router/top-k.
// ---------------------------------------------------------------------------

typedef _Float16 h16;
typedef _Float16 half8 __attribute__((ext_vector_type(8)));
typedef float f32x4 __attribute__((ext_vector_type(4)));

#define S_ 2048
#define H_ 2048
#define NH_ 16
#define D_ 128
#define E_ 8
#define TOPK_ 4
#define IE_ 1408
#define IS_ 5632
#define NQKV_ 6144

// Async global->LDS 16B copy. LDS dest is wave-uniform base + lane*16.
__device__ __forceinline__ void gload_lds16(const h16* g, h16* lds_base) {
  __builtin_amdgcn_global_load_lds(
      (const __attribute__((address_space(1))) void*)g,
      (__attribute__((address_space(3))) void*)lds_base, 16, 0, 0);
}

// ---------------------------------------------------------------------------
// Transpose fp32 (R x C) -> fp16 (C x R), batched over z.
// ---------------------------------------------------------------------------
__global__ __launch_bounds__(256) void transpose_kernel(
    const float* __restrict__ in, h16* __restrict__ out,
    int R, int C, long long inZ, long long outZ) {
  in  += (size_t)blockIdx.z * inZ;
  out += (size_t)blockIdx.z * outZ;
  __shared__ float tile[32][33];
  int c0 = blockIdx.x * 32, r0 = blockIdx.y * 32;
  int tx = threadIdx.x & 31, ty = threadIdx.x >> 5;  // 32 x 8
#pragma unroll
  for (int i = 0; i < 4; i++)
    tile[ty + 8 * i][tx] = in[(size_t)(r0 + ty + 8 * i) * C + c0 + tx];
  __syncthreads();
#pragma unroll
  for (int i = 0; i < 4; i++)
    out[(size_t)(c0 + ty + 8 * i) * R + r0 + tx] = (h16)tile[tx][ty + 8 * i];
}

// ---------------------------------------------------------------------------
// RMSNorm: one block per row. Writes fp16 (and optionally fp32).
// ---------------------------------------------------------------------------
template <bool F32OUT>
__global__ __launch_bounds__(256) void rmsnorm_kernel(
    const float* __restrict__ x, const float* __restrict__ w,
    h16* __restrict__ outh, float* __restrict__ outf) {
  int row = blockIdx.x;
  const float* xr = x + (size_t)row * H_;
  float ss = 0.f;
  for (int i = threadIdx.x; i < H_; i += 256) { float v = xr[i]; ss += v * v; }
  for (int o = 32; o > 0; o >>= 1) ss += __shfl_down(ss, o);
  __shared__ float sred[4];
  if ((threadIdx.x & 63) == 0) sred[threadIdx.x >> 6] = ss;
  __syncthreads();
  float tot = sred[0] + sred[1] + sred[2] + sred[3];
  float r = rsqrtf(tot * (1.0f / H_) + 1e-6f);
  for (int i = threadIdx.x; i < H_; i += 256) {
    float hv = xr[i] * r * w[i];
    outh[(size_t)row * H_ + i] = (h16)hv;
    if (F32OUT) outf[(size_t)row * H_ + i] = hv;
  }
}

// ---------------------------------------------------------------------------
// Generic MFMA GEMM: C[M,N] = A[M,K] * Bt[N,K]^T. A,Bt fp16, accum fp32.
// BM=BN=128, BK=32, 256 threads (4 waves, each 64x64 = 4x4 MFMA 16x16x32).
// m97-style: global_load_lds dwordx4 staging, unpadded LDS [128][32].
// STORE: 0 = fp32 store, 1 = fp16 store, 2 = atomicAdd(rowscale[row]*val).
// ---------------------------------------------------------------------------
template <int STORE, bool RESID>
__global__ __launch_bounds__(256, 2) void gemm_kernel(
    const h16* __restrict__ A, const h16* __restrict__ Bt, void* __restrict__ Cv,
    int M, int N, int K,
    const float* __restrict__ resid, const float* __restrict__ rowscale) {
  __shared__ __align__(16) h16 As[128 * 32];
  __shared__ __align__(16) h16 Bs[128 * 32];
  const int tid = threadIdx.x;
  const int wave = tid >> 6, lane = tid & 63;
  const int wm = wave >> 1, wn = wave & 1;
  const int quad = lane >> 4, l16 = lane & 15;
  const int row0 = blockIdx.x * 128, col0 = blockIdx.y * 128;

  f32x4 acc[4][4];
#pragma unroll
  for (int i = 0; i < 4; i++)
#pragma unroll
    for (int j = 0; j < 4; j++) acc[i][j] = (f32x4){0.f, 0.f, 0.f, 0.f};

  // staging: thread t, chunk i in {0,1}: row = (t>>2)+64i, k-chunk = (t&3)*8.
  // LDS offset = t*8 + i*2048 h16 -> wave-contiguous (base wave*512 + i*2048).
  const h16* Ap0 = A + (size_t)(row0 + (tid >> 2)) * K + (tid & 3) * 8;
  const h16* Bp0 = Bt + (size_t)(col0 + (tid >> 2)) * K + (tid & 3) * 8;
  h16* Asw = As + wave * 512;
  h16* Bsw = Bs + wave * 512;

  for (int k0 = 0; k0 < K; k0 += 32) {
    gload_lds16(Ap0 + k0, Asw);
    gload_lds16(Ap0 + k0 + (size_t)64 * K, Asw + 2048);
    gload_lds16(Bp0 + k0, Bsw);
    gload_lds16(Bp0 + k0 + (size_t)64 * K, Bsw + 2048);
    __syncthreads();
    half8 af[4], bfv[4];
#pragma unroll
    for (int mi = 0; mi < 4; mi++)
      af[mi] = *(const half8*)(As + (wm * 64 + mi * 16 + l16) * 32 + quad * 8);
#pragma unroll
    for (int ni = 0; ni < 4; ni++)
      bfv[ni] = *(const half8*)(Bs + (wn * 64 + ni * 16 + l16) * 32 + quad * 8);
#pragma unroll
    for (int mi = 0; mi < 4; mi++)
#pragma unroll
      for (int ni = 0; ni < 4; ni++)
        acc[mi][ni] = __builtin_amdgcn_mfma_f32_16x16x32_f16(af[mi], bfv[ni], acc[mi][ni], 0, 0, 0);
    __syncthreads();
  }

#pragma unroll
  for (int mi = 0; mi < 4; mi++) {
#pragma unroll
    for (int ni = 0; ni < 4; ni++) {
      int col = col0 + wn * 64 + ni * 16 + l16;
#pragma unroll
      for (int r = 0; r < 4; r++) {
        int row = row0 + wm * 64 + mi * 16 + quad * 4 + r;
        float val = acc[mi][ni][r];
        if (RESID) val += resid[(size_t)row * N + col];
        if (STORE == 0) ((float*)Cv)[(size_t)row * N + col] = val;
        else if (STORE == 1) ((h16*)Cv)[(size_t)row * N + col] = (h16)val;
        else atomicAdd(&((float*)Cv)[(size_t)row * N + col], rowscale[row] * val);
      }
    }
  }
}

// ---------------------------------------------------------------------------
// MoE GEMM. z = expert. PHASE 0: gathered A rows (rowidx) -> fp16 gu slots.
// PHASE 1: linear slot A rows -> atomicAdd roww[slot]*val into moe_acc[token].
// Invalid rows are clamped to row 0 (loaded, discarded at epilogue).
// ---------------------------------------------------------------------------
template <int PHASE>
__global__ __launch_bounds__(256, 2) void moe_gemm_kernel(
    const h16* __restrict__ A, const h16* __restrict__ BtAll, void* __restrict__ Cv,
    const int* __restrict__ offs, const int* __restrict__ cnt,
    const int* __restrict__ rowidx, const float* __restrict__ roww,
    int N, int K) {
  const int e = blockIdx.z;
  const int Me = cnt[e], offe = offs[e];
  const int row0 = blockIdx.x * 128;
  if (row0 >= Me) return;
  const int col0 = blockIdx.y * 128;
  const h16* Bt = BtAll + (size_t)e * N * K;

  __shared__ __align__(16) h16 As[128 * 32];
  __shared__ __align__(16) h16 Bs[128 * 32];
  const int tid = threadIdx.x;
  const int wave = tid >> 6, lane = tid & 63;
  const int wm = wave >> 1, wn = wave & 1;
  const int quad = lane >> 4, l16 = lane & 15;

  f32x4 acc[4][4];
#pragma unroll
  for (int i = 0; i < 4; i++)
#pragma unroll
    for (int j = 0; j < 4; j++) acc[i][j] = (f32x4){0.f, 0.f, 0.f, 0.f};

  size_t abase[2];
#pragma unroll
  for (int i = 0; i < 2; i++) {
    int row = (tid >> 2) + i * 64;
    bool valid = (row0 + row) < Me;
    int slot = offe + row0 + row;
    int ar = valid ? (PHASE == 0 ? rowidx[slot] : slot) : 0;
    abase[i] = (size_t)ar * K + (tid & 3) * 8;
  }
  const h16* Bp0 = Bt + (size_t)(col0 + (tid >> 2)) * K + (tid & 3) * 8;
  h16* Asw = As + wave * 512;
  h16* Bsw = Bs + wave * 512;

  for (int k0 = 0; k0 < K; k0 += 32) {
    gload_lds16(A + abase[0] + k0, Asw);
    gload_lds16(A + abase[1] + k0, Asw + 2048);
    gload_lds16(Bp0 + k0, Bsw);
    gload_lds16(Bp0 + k0 + (size_t)64 * K, Bsw + 2048);
    __syncthreads();
    half8 af[4], bfv[4];
#pragma unroll
    for (int mi = 0; mi < 4; mi++)
      af[mi] = *(const half8*)(As + (wm * 64 + mi * 16 + l16) * 32 + quad * 8);
#pragma unroll
    for (int ni = 0; ni < 4; ni++)
      bfv[ni] = *(const half8*)(Bs + (wn * 64 + ni * 16 + l16) * 32 + quad * 8);
#pragma unroll
    for (int mi = 0; mi < 4; mi++)
#pragma unroll
      for (int ni = 0; ni < 4; ni++)
        acc[mi][ni] = __builtin_amdgcn_mfma_f32_16x16x32_f16(af[mi], bfv[ni], acc[mi][ni], 0, 0, 0);
    __syncthreads();
  }

#pragma unroll
  for (int mi = 0; mi < 4; mi++) {
#pragma unroll
    for (int ni = 0; ni < 4; ni++) {
      int col = col0 + wn * 64 + ni * 16 + l16;
#pragma unroll
      for (int r = 0; r < 4; r++) {
        int lrow = wm * 64 + mi * 16 + quad * 4 + r;
        if (row0 + lrow < Me) {
          int slot = offe + row0 + lrow;
          float val = acc[mi][ni][r];
          if (PHASE == 0) {
            ((h16*)Cv)[(size_t)slot * N + col] = (h16)val;
          } else {
            int token = rowidx[slot];
            atomicAdd(&((float*)Cv)[(size_t)token * N + col], roww[slot] * val);
          }
        }
      }
    }
  }
}

// ---------------------------------------------------------------------------
// RoPE + bias: qkv fp32 -> Qh, Kh fp16 [s][h*128+d]. One thread per (s,h,d<64).
// ---------------------------------------------------------------------------
__global__ __launch_bounds__(256) void rope_kernel(
    const float* __restrict__ qkv, const float* __restrict__ bq,
    const float* __restrict__ bk, h16* __restrict__ Qh, h16* __restrict__ Kh) {
  int idx = blockIdx.x * 256 + threadIdx.x;
  int d = idx & 63;
  int h = (idx >> 6) & (NH_ - 1);
  int s = idx >> 10;
  float inv = powf(1.0e6f, -(float)d * (1.0f / 64.0f));
  float ang = (float)s * inv;
  float sn, c;
  sincosf(ang, &sn, &c);
  const float* base = qkv + (size_t)s * NQKV_;
  int iq = h * 128 + d;
  float q1 = base[iq] + bq[iq];
  float q2 = base[iq + 64] + bq[iq + 64];
  Qh[(size_t)s * H_ + iq] = (h16)(q1 * c - q2 * sn);
  Qh[(size_t)s * H_ + iq + 64] = (h16)(q2 * c + q1 * sn);
  float k1 = base[2048 + iq] + bk[iq];
  float k2 = base[2048 + iq + 64] + bk[iq + 64];
  Kh[(size_t)s * H_ + iq] = (h16)(k1 * c - k2 * sn);
  Kh[(size_t)s * H_ + iq + 64] = (h16)(k2 * c + k1 * sn);
}

// ---------------------------------------------------------------------------
// V transpose + bias: qkv fp32 -> Vt fp16 [h][d][s].
// ---------------------------------------------------------------------------
__global__ __launch_bounds__(256) void vtrans_kernel(
    const float* __restrict__ qkv, const float* __restrict__ bv,
    h16* __restrict__ Vt) {
  int h = blockIdx.z;
  __shared__ float tile[32][33];
  int c0 = blockIdx.x * 32;  // d
  int r0 = blockIdx.y * 32;  // s
  int tx = threadIdx.x & 31, ty = threadIdx.x >> 5;
#pragma unroll
  for (int i = 0; i < 4; i++)
    tile[ty + 8 * i][tx] =
        qkv[(size_t)(r0 + ty + 8 * i) * NQKV_ + 4096 + h * 128 + c0 + tx] +
        bv[h * 128 + c0 + tx];
  __syncthreads();
#pragma unroll
  for (int i = 0; i < 4; i++)
    Vt[(size_t)h * D_ * S_ + (size_t)(c0 + ty + 8 * i) * S_ + r0 + tx] =
        (h16)tile[tx][ty + 8 * i];
}

// ---------------------------------------------------------------------------
// MFMA flash attention, causal. Block = 64 q-rows of one head; 4 waves, each
// wave owns 16 q-rows. K-tile = 64. Q/K fragments direct from global (fp16,
// row-major [s][d]); V fragments direct from Vt [h][d][s]. P goes through a
// small per-wave LDS tile for the C-layout -> A-layout transform.
// ---------------------------------------------------------------------------
__global__ __launch_bounds__(256, 4) void attn_mfma_kernel(
    const h16* __restrict__ Qh, const h16* __restrict__ Kh,
    const h16* __restrict__ Vt, h16* __restrict__ attnh) {
  const int head = blockIdx.x & 15;
  const int qb = 31 - (blockIdx.x >> 4);  // heavy blocks first
  const int wave = threadIdx.x >> 6, lane = threadIdx.x & 63;
  const int quad = lane >> 4, l16 = lane & 15;
  const int q0 = qb * 64 + wave * 16;

  __shared__ __align__(16) h16 Plds[4][16][72];

  half8 qf[4];
#pragma unroll
  for (int kk = 0; kk < 4; kk++)
    qf[kk] = *(const half8*)&Qh[(size_t)(q0 + l16) * H_ + head * D_ + kk * 32 + quad * 8];

  f32x4 o[8];
#pragma unroll
  for (int i = 0; i < 8; i++) o[i] = (f32x4){0.f, 0.f, 0.f, 0.f};
  float m_i[4], l_i[4];
#pragma unroll
  for (int r = 0; r < 4; r++) { m_i[r] = -3.0e38f; l_i[r] = 0.f; }

  const float scale = 0.08838834764831845f;  // 1/sqrt(128)
  const h16* Kbase = Kh + head * D_;
  const h16* Vbase = Vt + (size_t)head * D_ * S_;

  for (int kc = 0; kc <= qb; kc++) {
    const int kb = kc * 64;
    f32x4 s[4];
#pragma unroll
    for (int ni = 0; ni < 4; ni++) s[ni] = (f32x4){0.f, 0.f, 0.f, 0.f};
#pragma unroll
    for (int ni = 0; ni < 4; ni++) {
#pragma unroll
      for (int kk = 0; kk < 4; kk++) {
        half8 bf = *(const half8*)&Kbase[(size_t)(kb + ni * 16 + l16) * H_ + kk * 32 + quad * 8];
        s[ni] = __builtin_amdgcn_mfma_f32_16x16x32_f16(qf[kk], bf, s[ni], 0, 0, 0);
      }
    }
    // scale + causal mask (mask only needed on diagonal tile)
    if (kc == qb) {
#pragma unroll
      for (int r = 0; r < 4; r++) {
        int row = q0 + quad * 4 + r;
#pragma unroll
        for (int ni = 0; ni < 4; ni++) {
          int col = kb + ni * 16 + l16;
          s[ni][r] = (col <= row) ? s[ni][r] * scale : -3.0e38f;
        }
      }
    } else {
#pragma unroll
      for (int ni = 0; ni < 4; ni++)
#pragma unroll
        for (int r = 0; r < 4; r++) s[ni][r] *= scale;
    }
    // online softmax: row stats across the 16 lanes of each quad group
    float alpha[4];
#pragma unroll
    for (int r = 0; r < 4; r++) {
      float mx = fmaxf(fmaxf(s[0][r], s[1][r]), fmaxf(s[2][r], s[3][r]));
      mx = fmaxf(mx, __shfl_xor(mx, 1));
      mx = fmaxf(mx, __shfl_xor(mx, 2));
      mx = fmaxf(mx, __shfl_xor(mx, 4));
      mx = fmaxf(mx, __shfl_xor(mx, 8));
      float mn = fmaxf(m_i[r], mx);
      alpha[r] = __expf(m_i[r] - mn);
      m_i[r] = mn;
    }
    float rsum[4] = {0.f, 0.f, 0.f, 0.f};
#pragma unroll
    for (int ni = 0; ni < 4; ni++) {
#pragma unroll
      for (int r = 0; r < 4; r++) {
        float p = __expf(s[ni][r] - m_i[r]);
        s[ni][r] = p;
        rsum[r] += p;
      }
    }
#pragma unroll
    for (int r = 0; r < 4; r++) {
      float t = rsum[r];
      t += __shfl_xor(t, 1);
      t += __shfl_xor(t, 2);
      t += __shfl_xor(t, 4);
      t += __shfl_xor(t, 8);
      l_i[r] = l_i[r] * alpha[r] + t;
    }
    // P (C-layout) -> LDS -> A-layout fragments
#pragma unroll
    for (int ni = 0; ni < 4; ni++)
#pragma unroll
      for (int r = 0; r < 4; r++)
        Plds[wave][quad * 4 + r][ni * 16 + l16] = (h16)s[ni][r];
    // rescale O
#pragma unroll
    for (int dt = 0; dt < 8; dt++)
#pragma unroll
      for (int r = 0; r < 4; r++) o[dt][r] *= alpha[r];
    half8 pf[2];
#pragma unroll
    for (int kk = 0; kk < 2; kk++)
      pf[kk] = *(const half8*)&Plds[wave][l16][kk * 32 + quad * 8];
#pragma unroll
    for (int dt = 0; dt < 8; dt++) {
#pragma unroll
      for (int kk = 0; kk < 2; kk++) {
        half8 vf = *(const half8*)&Vbase[(size_t)(dt * 16 + l16) * S_ + kb + kk * 32 + quad * 8];
        o[dt] = __builtin_amdgcn_mfma_f32_16x16x32_f16(pf[kk], vf, o[dt], 0, 0, 0);
      }
    }
  }
#pragma unroll
  for (int r = 0; r < 4; r++) {
    float inv = 1.0f / l_i[r];
    size_t rowb = (size_t)(q0 + quad * 4 + r) * H_ + head * D_;
#pragma unroll
    for (int dt = 0; dt < 8; dt++)
      attnh[rowb + dt * 16 + l16] = (h16)(o[dt][r] * inv);
  }
}

// ---------------------------------------------------------------------------
// Router: fp32 logits, softmax, top-4 (tie -> lower index), sigmoid(sgate).
// One wave per token.
// ---------------------------------------------------------------------------
__global__ __launch_bounds__(256) void router_kernel(
    const float* __restrict__ h2f, const float* __restrict__ gate_w,
    const float* __restrict__ sgate_w, float* __restrict__ logits_out,
    int* __restrict__ sel4, float* __restrict__ rw4, float* __restrict__ sgs) {
  int token = blockIdx.x * 4 + (threadIdx.x >> 6);
  int lane = threadIdx.x & 63;
  const float* hrow = h2f + (size_t)token * H_;
  float acc[8] = {0, 0, 0, 0, 0, 0, 0, 0};
  float accs = 0.f;
  for (int i = lane; i < H_; i += 64) {
    float hv = hrow[i];
    const float* g = gate_w + (size_t)i * E_;
#pragma unroll
    for (int e = 0; e < 8; e++) acc[e] += hv * g[e];
    accs += hv * sgate_w[i];
  }
#pragma unroll
  for (int e = 0; e < 8; e++)
    for (int m = 32; m > 0; m >>= 1) acc[e] += __shfl_xor(acc[e], m);
  for (int m = 32; m > 0; m >>= 1) accs += __shfl_xor(accs, m);
  if (lane == 0) {
    float mx = acc[0];
#pragma unroll
    for (int e = 1; e < 8; e++) mx = fmaxf(mx, acc[e]);
    float p[8], sum = 0.f;
#pragma unroll
    for (int e = 0; e < 8; e++) { p[e] = expf(acc[e] - mx); sum += p[e]; }
    float isum = 1.f / sum;
#pragma unroll
    for (int e = 0; e < 8; e++) {
      p[e] *= isum;
      logits_out[(size_t)token * E_ + e] = acc[e];
    }
    bool used[8] = {false, false, false, false, false, false, false, false};
    for (int k = 0; k < TOPK_; k++) {
      int best = -1; float bv = -1.f;
      for (int e = 0; e < 8; e++)
        if (!used[e] && p[e] > bv) { bv = p[e]; best = e; }
      used[best] = true;
      sel4[token * TOPK_ + k] = best;
      rw4[token * TOPK_ + k] = bv;
    }
    sgs[token] = 1.f / (1.f + expf(-accs));
  }
}

__global__ __launch_bounds__(256) void count_kernel(const int* __restrict__ sel4,
                                                    int* __restrict__ cnt) {
  int s = blockIdx.x * 256 + threadIdx.x;
  if (s >= S_) return;
#pragma unroll
  for (int j = 0; j < TOPK_; j++) atomicAdd(&cnt[sel4[s * TOPK_ + j]], 1);
}

__global__ void offsets_kernel(const int* __restrict__ cnt, int* __restrict__ offs,
                               int* __restrict__ cursor) {
  if (threadIdx.x == 0 && blockIdx.x == 0) {
    int a = 0;
    for (int e = 0; e < E_; e++) { offs[e] = a; cursor[e] = a; a += cnt[e]; }
  }
}

__global__ __launch_bounds__(256) void fill_kernel(
    const int* __restrict__ sel4, const float* __restrict__ rw4,
    int* __restrict__ cursor, int* __restrict__ rowidx, float* __restrict__ roww) {
  int s = blockIdx.x * 256 + threadIdx.x;
  if (s >= S_) return;
  for (int j = 0; j < TOPK_; j++) {
    int e = sel4[s * TOPK_ + j];
    int pos = atomicAdd(&cursor[e], 1);
    rowidx[pos] = s;
    roww[pos] = rw4[s * TOPK_ + j];
  }
}

// ---------------------------------------------------------------------------
// silu(gate)*up, fp16 in/out. gu row = [gate (W) | up (W)].
// ---------------------------------------------------------------------------
template <int W>
__global__ __launch_bounds__(256) void silu_mul_kernel(
    const h16* __restrict__ gu, h16* __restrict__ act, long long total) {
  long long idx = (long long)blockIdx.x * 256 + threadIdx.x;
  if (idx >= total) return;
  int row = (int)(idx / W);
  int col = (int)(idx % W);
  float g = (float)gu[(size_t)row * (2 * W) + col];
  float u = (float)gu[(size_t)row * (2 * W) + W + col];
  float a = g / (1.f + expf(-g)) * u;
  act[idx] = (h16)a;
}

__global__ __launch_bounds__(256) void final_add_kernel(
    const float4* __restrict__ x2, const float4* __restrict__ acc,
    float4* __restrict__ out) {
  int i = blockIdx.x * 256 + threadIdx.x;
  float4 a = x2[i], b = acc[i];
  float4 r;
  r.x = a.x + b.x; r.y = a.y + b.y; r.z = a.z + b.z; r.w = a.w + b.w;
  out[i] = r;
}

// ---------------------------------------------------------------------------
extern "C" void kernel_launch(void* const* d_in, const int* in_sizes, int n_in,
                              void* d_out, int out_size, void* d_ws, size_t ws_size,
                              hipStream_t stream) {
  const float* x      = (const float*)d_in[0];
  const float* ln1    = (const float*)d_in[1];
  const float* ln2    = (const float*)d_in[2];
  const float* wq     = (const float*)d_in[3];
  const float* bq     = (const float*)d_in[4];
  const float* wk     = (const float*)d_in[5];
  const float* bk     = (const float*)d_in[6];
  const float* wv     = (const float*)d_in[7];
  const float* bv     = (const float*)d_in[8];
  const float* wo     = (const float*)d_in[9];
  const float* gatew  = (const float*)d_in[10];
  const float* eg     = (const float*)d_in[11];
  const float* eu     = (const float*)d_in[12];
  const float* ed     = (const float*)d_in[13];
  const float* sg     = (const float*)d_in[14];
  const float* su     = (const float*)d_in[15];
  const float* sd     = (const float*)d_in[16];
  const float* sgate  = (const float*)d_in[17];
  float* out = (float*)d_out;

  // ---- workspace layout (~334 MB) ----
  char* w = (char*)d_ws;
  size_t off = 0;
  auto alloc = [&](size_t n) {
    char* p = w + off;
    off += (n + 255) & ~(size_t)255;
    return p;
  };
  h16* h1h     = (h16*)alloc((size_t)S_ * H_ * 2);
  float* qkv   = (float*)alloc((size_t)S_ * NQKV_ * 4);
  h16* attnh   = (h16*)alloc((size_t)S_ * H_ * 2);
  float* x2    = (float*)alloc((size_t)S_ * H_ * 4);
  h16* h2h     = (h16*)alloc((size_t)S_ * H_ * 2);
  float* h2f   = (float*)alloc((size_t)S_ * H_ * 4);
  float* sgs   = (float*)alloc((size_t)S_ * 4);
  int* sel4    = (int*)alloc((size_t)S_ * TOPK_ * 4);
  float* rw4   = (float*)alloc((size_t)S_ * TOPK_ * 4);
  int* cnt     = (int*)alloc(96);  // cnt[8] | offs[8] | cursor[8]
  int* offs    = cnt + 8;
  int* cursor  = cnt + 16;
  int* rowidx  = (int*)alloc(8192 * 4);
  float* roww  = (float*)alloc(8192 * 4);
  float* moeac = (float*)alloc((size_t)S_ * H_ * 4);
  char* WAR    = alloc(138412032);  // weight arena (max: eguT+edT)
  char* GAR    = alloc(69206016);   // gate-up / act arena (also Qh/Kh/Vt)

  h16* qkvT = (h16*)WAR;                                  // 6144 x 2048
  h16* woT  = (h16*)(WAR + (size_t)NQKV_ * H_ * 2);       // 2048 x 2048
  h16* sguT = (h16*)WAR;                                  // 11264 x 2048
  h16* sdT  = (h16*)(WAR + (size_t)2 * IS_ * H_ * 2);     // 2048 x 5632
  h16* eguT = (h16*)WAR;                                  // 8 x 2816 x 2048
  h16* edT  = (h16*)(WAR + (size_t)E_ * 2 * IE_ * H_ * 2);// 8 x 2048 x 1408
  h16* gu_s = (h16*)GAR;
  h16* act_s = (h16*)(GAR + (size_t)S_ * 2 * IS_ * 2);
  h16* gu_e = (h16*)GAR;
  h16* act_e = (h16*)(GAR + (size_t)8192 * 2 * IE_ * 2);
  // attention fp16 buffers live in GAR (dead before shared-expert stage)
  h16* Qh = (h16*)GAR;
  h16* Kh = (h16*)(GAR + (size_t)S_ * H_ * 2);
  h16* Vt = (h16*)(GAR + (size_t)2 * S_ * H_ * 2);

  // ---- init ----
  hipMemsetAsync(cnt, 0, 32, stream);
  hipMemsetAsync(moeac, 0, (size_t)S_ * H_ * 4, stream);

  // ---- stage A weights: qkv + wo ----
  transpose_kernel<<<dim3(64, 64, 1), 256, 0, stream>>>(wq, qkvT, H_, H_, 0, 0);
  transpose_kernel<<<dim3(64, 64, 1), 256, 0, stream>>>(wk, qkvT + (size_t)H_ * H_, H_, H_, 0, 0);
  transpose_kernel<<<dim3(64, 64, 1), 256, 0, stream>>>(wv, qkvT + (size_t)2 * H_ * H_, H_, H_, 0, 0);
  transpose_kernel<<<dim3(64, 64, 1), 256, 0, stream>>>(wo, woT, H_, H_, 0, 0);

  // ---- attention path ----
  rmsnorm_kernel<false><<<S_, 256, 0, stream>>>(x, ln1, h1h, nullptr);
  gemm_kernel<0, false><<<dim3(16, 48), 256, 0, stream>>>(
      h1h, qkvT, qkv, S_, NQKV_, H_, nullptr, nullptr);
  rope_kernel<<<(S_ * NH_ * 64) / 256, 256, 0, stream>>>(qkv, bq, bk, Qh, Kh);
  vtrans_kernel<<<dim3(4, 64, 16), 256, 0, stream>>>(qkv, bv, Vt);
  attn_mfma_kernel<<<512, 256, 0, stream>>>(Qh, Kh, Vt, attnh);
  gemm_kernel<0, true><<<dim3(16, 16), 256, 0, stream>>>(
      attnh, woT, x2, S_, H_, H_, x, nullptr);

  // ---- router ----
  rmsnorm_kernel<true><<<S_, 256, 0, stream>>>(x2, ln2, h2h, h2f);
  router_kernel<<<S_ / 4, 256, 0, stream>>>(h2f, gatew, sgate,
                                            out + (size_t)S_ * H_, sel4, rw4, sgs);
  count_kernel<<<S_ / 256, 256, 0, stream>>>(sel4, cnt);
  offsets_kernel<<<1, 64, 0, stream>>>(cnt, offs, cursor);
  fill_kernel<<<S_ / 256, 256, 0, stream>>>(sel4, rw4, cursor, rowidx, roww);

  // ---- shared expert ----
  transpose_kernel<<<dim3(176, 64, 1), 256, 0, stream>>>(sg, sguT, H_, IS_, 0, 0);
  transpose_kernel<<<dim3(176, 64, 1), 256, 0, stream>>>(su, sguT + (size_t)IS_ * H_, H_, IS_, 0, 0);
  transpose_kernel<<<dim3(64, 176, 1), 256, 0, stream>>>(sd, sdT, IS_, H_, 0, 0);
  gemm_kernel<1, false><<<dim3(16, 88), 256, 0, stream>>>(
      h2h, sguT, gu_s, S_, 2 * IS_, H_, nullptr, nullptr);
  {
    long long tot = (long long)S_ * IS_;
    silu_mul_kernel<IS_><<<(unsigned)((tot + 255) / 256), 256, 0, stream>>>(gu_s, act_s, tot);
  }
  gemm_kernel<2, false><<<dim3(16, 16), 256, 0, stream>>>(
      act_s, sdT, moeac, S_, H_, IS_, nullptr, sgs);

  // ---- routed experts ----
  transpose_kernel<<<dim3(44, 64, 8), 256, 0, stream>>>(
      eg, eguT, H_, IE_, (long long)H_ * IE_, (long long)2 * IE_ * H_);
  transpose_kernel<<<dim3(44, 64, 8), 256, 0, stream>>>(
      eu, eguT + (size_t)IE_ * H_, H_, IE_, (long long)H_ * IE_, (long long)2 * IE_ * H_);
  transpose_kernel<<<dim3(64, 44, 8), 256, 0, stream>>>(
      ed, edT, IE_, H_, (long long)IE_ * H_, (long long)H_ * IE_);
  moe_gemm_kernel<0><<<dim3(16, 22, 8), 256, 0, stream>>>(
      h2h, eguT, gu_e, offs, cnt, rowidx, roww, 2 * IE_, H_);
  {
    long long tot = (long long)8192 * IE_;
    silu_mul_kernel<IE_><<<(unsigned)((tot + 255) / 256), 256, 0, stream>>>(gu_e, act_e, tot);
  }
  moe_gemm_kernel<1><<<dim3(16, 16, 8), 256, 0, stream>>>(
      act_e, edT, moeac, offs, cnt, rowidx, roww, H_, IE_);

  // ---- output ----
  final_add_kernel<<<(S_ * H_) / 1024, 256, 0, stream>>>(
      (const float4*)x2, (const float4*)moeac, (float4*)out);
}